// Round 1
// baseline (567.657 us; speedup 1.0000x reference)
//
#include <hip/hip_runtime.h>

typedef unsigned short ushort_t;
typedef float  f32x4  __attribute__((ext_vector_type(4)));
typedef __bf16 bf16x8 __attribute__((ext_vector_type(8)));

#define MFMA16(a,b,c) __builtin_amdgcn_mfma_f32_16x16x32_bf16((a),(b),(c),0,0,0)

__device__ __forceinline__ ushort_t f2bf(float f) {
  union { float f; unsigned u; } v; v.f = f;
  unsigned u = v.u;
  unsigned r = u + 0x7FFFu + ((u >> 16) & 1u);   // round-to-nearest-even
  return (ushort_t)(r >> 16);
}
__device__ __forceinline__ float bf2f(ushort_t s) {
  union { unsigned u; float f; } v; v.u = ((unsigned)s) << 16;
  return v.f;
}

// ---------------------------------------------------------------------------
// Kernel 1: x [8][512][2048] f32  ->  xT [8][2048][512] bf16 (p-major, cin contig)
// ---------------------------------------------------------------------------
__global__ __launch_bounds__(256) void xpose_cast(const float* __restrict__ x,
                                                  ushort_t* __restrict__ xT) {
  __shared__ __align__(16) ushort_t T[64 * 72];
  int pt = blockIdx.x, ct = blockIdx.y, b = blockIdx.z;
  int tid = threadIdx.x;
  const float* src = x + ((size_t)b * 512 + ct * 64) * 2048 + pt * 64;
#pragma unroll
  for (int r = 0; r < 4; ++r) {
    int chunk = tid + 256 * r;
    int cc = chunk >> 4, ch = chunk & 15;
    float4 v = *(const float4*)&src[(size_t)cc * 2048 + ch * 4];
    T[(ch * 4 + 0) * 72 + cc] = f2bf(v.x);
    T[(ch * 4 + 1) * 72 + cc] = f2bf(v.y);
    T[(ch * 4 + 2) * 72 + cc] = f2bf(v.z);
    T[(ch * 4 + 3) * 72 + cc] = f2bf(v.w);
  }
  __syncthreads();
  ushort_t* dstb = xT + ((size_t)b * 2048 + pt * 64) * 512 + ct * 64;
#pragma unroll
  for (int r = 0; r < 2; ++r) {
    int chunk = tid + 256 * r;
    int pp = chunk >> 3, ch = chunk & 7;
    *(uint4*)&dstb[(size_t)pp * 512 + ch * 8] = *(const uint4*)&T[pp * 72 + ch * 8];
  }
}

// ---------------------------------------------------------------------------
// Kernel 2: grouped conv (MFMA) + bias; writes unnormalized y (bf16) in final
// layouts; accumulates GroupNorm partial sums via atomics.
// grid (pc=16, ng=32, b*br=24), 256 thr.
// Q branch -> [B][C][P]; K/V branches -> [B][H][P][128].
// ---------------------------------------------------------------------------
__global__ __launch_bounds__(256) void conv_gn(
    const ushort_t* __restrict__ xT,
    const float* __restrict__ wq, const float* __restrict__ wk, const float* __restrict__ wv,
    const float* __restrict__ bq, const float* __restrict__ bk, const float* __restrict__ bv,
    ushort_t* __restrict__ Qb, ushort_t* __restrict__ Kb, ushort_t* __restrict__ Vb,
    float* __restrict__ stats) {
  int pc = blockIdx.x;
  int ng = blockIdx.y;
  int bz = blockIdx.z;
  int b = bz & 7, br = bz >> 3;
  const float* w    = (br == 0) ? wq : ((br == 1) ? wk : wv);
  const float* bias = (br == 0) ? bq : ((br == 1) ? bk : bv);
  ushort_t* dst     = (br == 0) ? Qb : ((br == 1) ? Kb : Vb);
  int g = ng >> 2;            // conv group == head
  int co0 = ng << 5;
  int tid = threadIdx.x, lane = tid & 63, wid = tid >> 6;
  int l15 = lane & 15, q = lane >> 4;

  __shared__ __align__(16) ushort_t wl[32 * 72];
  __shared__ __align__(16) ushort_t xl[128 * 72];
  __shared__ __align__(16) ushort_t yl[5120];
  __shared__ float biasl[32];
  __shared__ float redbuf[8];

  // stage weights: 32 rows x 64 f (2048 f32)
#pragma unroll
  for (int r = 0; r < 2; ++r) {
    int idx = (tid + 256 * r) << 2;
    float4 v = *(const float4*)&w[(size_t)co0 * 64 + idx];
    int row = idx >> 6, f = idx & 63;
    wl[row * 72 + f + 0] = f2bf(v.x);
    wl[row * 72 + f + 1] = f2bf(v.y);
    wl[row * 72 + f + 2] = f2bf(v.z);
    wl[row * 72 + f + 3] = f2bf(v.w);
  }
  if (tid < 32) biasl[tid] = bias[co0 + tid];
  // stage xT tile: 128 p-rows x 64 f (bf16), transposed layout [p][f]
  const ushort_t* xsrc = xT + ((size_t)b * 2048 + pc * 128) * 512 + g * 64;
#pragma unroll
  for (int r = 0; r < 4; ++r) {
    int chunk = tid + 256 * r;
    int row = chunk >> 3, ch = chunk & 7;
    *(uint4*)&xl[row * 72 + ch * 8] = *(const uint4*)&xsrc[(size_t)row * 512 + ch * 8];
  }
  __syncthreads();

  float bias_r[2][4];
#pragma unroll
  for (int m = 0; m < 2; ++m)
#pragma unroll
    for (int rg = 0; rg < 4; ++rg) bias_r[m][rg] = biasl[m * 16 + 4 * q + rg];

  bf16x8 Af[2][2];
#pragma unroll
  for (int m = 0; m < 2; ++m)
#pragma unroll
    for (int kk = 0; kk < 2; ++kk)
      Af[m][kk] = *(const bf16x8*)&wl[(m * 16 + l15) * 72 + kk * 32 + q * 8];

  f32x4 acc[2][2];
#pragma unroll
  for (int m = 0; m < 2; ++m)
#pragma unroll
    for (int n2 = 0; n2 < 2; ++n2) acc[m][n2] = (f32x4){0.f, 0.f, 0.f, 0.f};

#pragma unroll
  for (int n2 = 0; n2 < 2; ++n2)
#pragma unroll
    for (int kk = 0; kk < 2; ++kk) {
      bf16x8 Bf = *(const bf16x8*)&xl[((wid * 2 + n2) * 16 + l15) * 72 + kk * 32 + q * 8];
#pragma unroll
      for (int m = 0; m < 2; ++m) acc[m][n2] = MFMA16(Af[m][kk], Bf, acc[m][n2]);
    }

  float s1 = 0.f, s2 = 0.f;
#pragma unroll
  for (int m = 0; m < 2; ++m)
#pragma unroll
    for (int n2 = 0; n2 < 2; ++n2)
#pragma unroll
      for (int rg = 0; rg < 4; ++rg) {
        float y = acc[m][n2][rg] + bias_r[m][rg];
        acc[m][n2][rg] = y;
        s1 += y; s2 += y * y;
      }

  if (br == 0) {   // yl: [32 c][136 p]
#pragma unroll
    for (int m = 0; m < 2; ++m)
#pragma unroll
      for (int n2 = 0; n2 < 2; ++n2)
#pragma unroll
        for (int rg = 0; rg < 4; ++rg)
          yl[(m * 16 + 4 * q + rg) * 136 + (wid * 2 + n2) * 16 + l15] = f2bf(acc[m][n2][rg]);
  } else {         // yl: [128 p][40 c]
#pragma unroll
    for (int m = 0; m < 2; ++m)
#pragma unroll
      for (int n2 = 0; n2 < 2; ++n2)
#pragma unroll
        for (int rg = 0; rg < 4; ++rg)
          yl[((wid * 2 + n2) * 16 + l15) * 40 + m * 16 + 4 * q + rg] = f2bf(acc[m][n2][rg]);
  }
  __syncthreads();

  if (br == 0) {
#pragma unroll
    for (int r = 0; r < 2; ++r) {
      int chunk = tid + 256 * r;
      int row = chunk >> 4, ch = chunk & 15;
      *(uint4*)&dst[((size_t)b * 1024 + co0 + row) * 2048 + pc * 128 + ch * 8] =
          *(const uint4*)&yl[row * 136 + ch * 8];
    }
  } else {
    int h = ng >> 2, cih0 = (ng & 3) << 5;
#pragma unroll
    for (int r = 0; r < 2; ++r) {
      int chunk = tid + 256 * r;
      int row = chunk >> 2, ch = chunk & 3;
      *(uint4*)&dst[((size_t)(b * 8 + h) * 2048 + pc * 128 + row) * 128 + cih0 + ch * 8] =
          *(const uint4*)&yl[row * 40 + ch * 8];
    }
  }

#pragma unroll
  for (int mask = 32; mask >= 1; mask >>= 1) {
    s1 += __shfl_xor(s1, mask, 64);
    s2 += __shfl_xor(s2, mask, 64);
  }
  if (lane == 0) { redbuf[wid * 2] = s1; redbuf[wid * 2 + 1] = s2; }
  __syncthreads();
  if (tid == 0) {
    float S1 = redbuf[0] + redbuf[2] + redbuf[4] + redbuf[6];
    float S2 = redbuf[1] + redbuf[3] + redbuf[5] + redbuf[7];
    int sidx = (br * 8 + b) * 32 + ng;
    atomicAdd(&stats[2 * sidx], S1);
    atomicAdd(&stats[2 * sidx + 1], S2);
  }
}

// ---------------------------------------------------------------------------
// Kernel 3: in-place GroupNorm affine + LeakyReLU over the 3 contiguous bufs.
// ---------------------------------------------------------------------------
__global__ __launch_bounds__(256) void gn_apply(
    ushort_t* __restrict__ buf, const float* __restrict__ stats,
    const float* __restrict__ gw1, const float* __restrict__ gb1,
    const float* __restrict__ gw2, const float* __restrict__ gb2,
    const float* __restrict__ gw3, const float* __restrict__ gb3) {
  const unsigned NQ = 16777216u;
  unsigned gid = blockIdx.x * 256 + threadIdx.x;
  unsigned e = gid * 8;
  int br; unsigned local;
  if (e < NQ)            { br = 0; local = e; }
  else if (e < 2u * NQ)  { br = 1; local = e - NQ; }
  else                   { br = 2; local = e - 2u * NQ; }
  int b, c0;
  if (br == 0) { b = local >> 21; c0 = (local >> 11) & 1023; }
  else {
    int cih = local & 127; int h = (local >> 18) & 7;
    b = local >> 21; c0 = h * 128 + cih;
  }
  int ng = c0 >> 5;
  const float* gw = (br == 0) ? gw1 : ((br == 1) ? gw2 : gw3);
  const float* gb = (br == 0) ? gb1 : ((br == 1) ? gb2 : gb3);
  int sidx = (br * 8 + b) * 32 + ng;
  float mean = stats[2 * sidx] * (1.f / 65536.f);
  float var  = stats[2 * sidx + 1] * (1.f / 65536.f) - mean * mean;
  float rstd = rsqrtf(var + 1e-5f);
  uint4 d = *(uint4*)&buf[(size_t)e];
  ushort_t* pu = (ushort_t*)&d;
#pragma unroll
  for (int i = 0; i < 8; ++i) {
    int ci = (br == 0) ? c0 : (c0 + i);
    float a = rstd * gw[ci];
    float b2 = gb[ci] - mean * a;
    float yn = fmaf(bf2f(pu[i]), a, b2);
    yn = (yn >= 0.f) ? yn : 0.1f * yn;
    pu[i] = f2bf(yn);
  }
  *(uint4*)&buf[(size_t)e] = d;
}

// ---------------------------------------------------------------------------
// Kernel 4: flash attention. flashQ=K-branch [B,H,P,128], flashK=V-branch
// [B,H,P,128], flashV=Q-branch [B,C,P]. i-tile 128, j-tile 64, 4 waves x 32 rows.
// ---------------------------------------------------------------------------
__global__ __launch_bounds__(256, 2) void attn(
    const ushort_t* __restrict__ Qb, const ushort_t* __restrict__ Kb,
    const ushort_t* __restrict__ Vb, float* __restrict__ out) {
  __shared__ __align__(16) ushort_t smem[35840];   // 71680 B
  ushort_t* Qs  = smem;            // [128][136] flashQ tile
  ushort_t* Vs  = smem + 17408;    // [128][72]  flashV tile, [c][j]
  ushort_t* KPs = smem + 26624;    // union: Ks [64][136] / Ps [128][72]
  float* Os = (float*)smem;        // [128][132] epilogue staging

  int it = blockIdx.x, bh = blockIdx.y;
  int tid = threadIdx.x, lane = tid & 63, wid = tid >> 6;
  int l15 = lane & 15, q = lane >> 4;
  const float scale = 0.08838834764831845f;   // 1/sqrt(128)

  const ushort_t* fQ = Kb + ((size_t)bh * 2048 + it * 128) * 128;
#pragma unroll
  for (int r = 0; r < 8; ++r) {
    int chunk = tid + 256 * r;
    int row = chunk >> 4, ch = chunk & 15;
    *(uint4*)&Qs[row * 136 + ch * 8] = *(const uint4*)&fQ[(size_t)row * 128 + ch * 8];
  }
  __syncthreads();

  bf16x8 Aq[2][4];   // resident flashQ fragments for whole j-loop
#pragma unroll
  for (int m = 0; m < 2; ++m)
#pragma unroll
    for (int kk = 0; kk < 4; ++kk)
      Aq[m][kk] = *(const bf16x8*)&Qs[(wid * 32 + m * 16 + l15) * 136 + kk * 32 + q * 8];

  float mrow[2][4], lrow[2][4];
  f32x4 O[2][8];
#pragma unroll
  for (int m = 0; m < 2; ++m)
#pragma unroll
    for (int rg = 0; rg < 4; ++rg) { mrow[m][rg] = -1e30f; lrow[m][rg] = 0.f; }
#pragma unroll
  for (int m = 0; m < 2; ++m)
#pragma unroll
    for (int cn = 0; cn < 8; ++cn) O[m][cn] = (f32x4){0.f, 0.f, 0.f, 0.f};

  for (int jt = 0; jt < 32; ++jt) {
    const ushort_t* fK = Vb + ((size_t)bh * 2048 + jt * 64) * 128;
    const ushort_t* fV = Qb + (size_t)bh * 128 * 2048 + jt * 64;
#pragma unroll
    for (int r = 0; r < 4; ++r) {
      int chunk = tid + 256 * r;
      { int row = chunk >> 4, ch = chunk & 15;
        *(uint4*)&KPs[row * 136 + ch * 8] = *(const uint4*)&fK[(size_t)row * 128 + ch * 8]; }
      { int row = chunk >> 3, ch = chunk & 7;
        *(uint4*)&Vs[row * 72 + ch * 8] = *(const uint4*)&fV[(size_t)row * 2048 + ch * 8]; }
    }
    __syncthreads();

    // S = flashQ . flashK^T   (B supplied as [N][K] rows, m97 gemm_bt pattern)
    f32x4 S[2][4];
#pragma unroll
    for (int m = 0; m < 2; ++m)
#pragma unroll
      for (int n = 0; n < 4; ++n) S[m][n] = (f32x4){0.f, 0.f, 0.f, 0.f};
#pragma unroll
    for (int kk = 0; kk < 4; ++kk)
#pragma unroll
      for (int n = 0; n < 4; ++n) {
        bf16x8 Bk = *(const bf16x8*)&KPs[(n * 16 + l15) * 136 + kk * 32 + q * 8];
        S[0][n] = MFMA16(Aq[0][kk], Bk, S[0][n]);
        S[1][n] = MFMA16(Aq[1][kk], Bk, S[1][n]);
      }

    // online softmax (rows r = 4q+rg; cols across l15 + 4 n-tiles)
    float al[2][4];
#pragma unroll
    for (int m = 0; m < 2; ++m)
#pragma unroll
      for (int rg = 0; rg < 4; ++rg) {
        float v0 = fmaxf(fmaxf(S[m][0][rg], S[m][1][rg]),
                         fmaxf(S[m][2][rg], S[m][3][rg])) * scale;
        v0 = fmaxf(v0, __shfl_xor(v0, 1, 64));
        v0 = fmaxf(v0, __shfl_xor(v0, 2, 64));
        v0 = fmaxf(v0, __shfl_xor(v0, 4, 64));
        v0 = fmaxf(v0, __shfl_xor(v0, 8, 64));
        float mn = fmaxf(mrow[m][rg], v0);
        float a = __expf(mrow[m][rg] - mn);
        mrow[m][rg] = mn;
        al[m][rg] = a;
        float rs = 0.f;
#pragma unroll
        for (int n = 0; n < 4; ++n) {
          float p = __expf(fmaf(S[m][n][rg], scale, -mn));
          S[m][n][rg] = p;
          rs += p;
        }
        rs += __shfl_xor(rs, 1, 64);
        rs += __shfl_xor(rs, 2, 64);
        rs += __shfl_xor(rs, 4, 64);
        rs += __shfl_xor(rs, 8, 64);
        lrow[m][rg] = lrow[m][rg] * a + rs;
      }
#pragma unroll
    for (int m = 0; m < 2; ++m)
#pragma unroll
      for (int cn = 0; cn < 8; ++cn)
#pragma unroll
        for (int rg = 0; rg < 4; ++rg) O[m][cn][rg] *= al[m][rg];

    __syncthreads();   // all waves done reading Ks before P overwrites it
#pragma unroll
    for (int m = 0; m < 2; ++m)
#pragma unroll
      for (int n = 0; n < 4; ++n)
#pragma unroll
        for (int rg = 0; rg < 4; ++rg)
          KPs[(wid * 32 + m * 16 + 4 * q + rg) * 72 + n * 16 + l15] = f2bf(S[m][n][rg]);
    __syncthreads();   // P visible

    // O += P . flashV   (Vs is [c][j] = B as [N][K])
#pragma unroll
    for (int kk = 0; kk < 2; ++kk) {
      bf16x8 Ap[2];
      Ap[0] = *(const bf16x8*)&KPs[(wid * 32 + 0 * 16 + l15) * 72 + kk * 32 + q * 8];
      Ap[1] = *(const bf16x8*)&KPs[(wid * 32 + 1 * 16 + l15) * 72 + kk * 32 + q * 8];
#pragma unroll
      for (int cn = 0; cn < 8; ++cn) {
        bf16x8 Bv = *(const bf16x8*)&Vs[(cn * 16 + l15) * 72 + kk * 32 + q * 8];
        O[0][cn] = MFMA16(Ap[0], Bv, O[0][cn]);
        O[1][cn] = MFMA16(Ap[1], Bv, O[1][cn]);
      }
    }
    __syncthreads();   // before next staging overwrites KPs/Vs
  }

  // epilogue: divide by l, transpose via LDS, coalesced store
#pragma unroll
  for (int m = 0; m < 2; ++m)
#pragma unroll
    for (int rg = 0; rg < 4; ++rg) {
      float inv = 1.f / lrow[m][rg];
#pragma unroll
      for (int cn = 0; cn < 8; ++cn)
        Os[(cn * 16 + l15) * 132 + wid * 32 + m * 16 + 4 * q + rg] = O[m][cn][rg] * inv;
    }
  __syncthreads();
  float* obase = out + (size_t)bh * 128 * 2048 + it * 128;
#pragma unroll
  for (int r = 0; r < 16; ++r) {
    int chunk = tid + 256 * r;
    int row = chunk >> 5, ch = chunk & 31;
    *(float4*)&obase[(size_t)row * 2048 + ch * 4] = *(const float4*)&Os[row * 132 + ch * 4];
  }
}

// ---------------------------------------------------------------------------
extern "C" void kernel_launch(void* const* d_in, const int* in_sizes, int n_in,
                              void* d_out, int out_size, void* d_ws, size_t ws_size,
                              hipStream_t stream) {
  const float* x   = (const float*)d_in[0];
  const float* wq  = (const float*)d_in[1];
  const float* bq  = (const float*)d_in[2];
  const float* gw1 = (const float*)d_in[3];
  const float* gb1 = (const float*)d_in[4];
  const float* wk  = (const float*)d_in[5];
  const float* bk  = (const float*)d_in[6];
  const float* gw2 = (const float*)d_in[7];
  const float* gb2 = (const float*)d_in[8];
  const float* wv  = (const float*)d_in[9];
  const float* bv  = (const float*)d_in[10];
  const float* gw3 = (const float*)d_in[11];
  const float* gb3 = (const float*)d_in[12];
  float* out = (float*)d_out;
  char* ws = (char*)d_ws;

  ushort_t* Qb = (ushort_t*)(ws);               // 33,554,432 B  [B,C,P] bf16
  ushort_t* Kb = (ushort_t*)(ws + 33554432);    // 33,554,432 B  [B,H,P,128] bf16
  ushort_t* Vb = (ushort_t*)(ws + 67108864);    // 33,554,432 B  [B,H,P,128] bf16
  ushort_t* xT = (ushort_t*)(ws + 100663296);   // 16,777,216 B  [B,P,Cin] bf16
  float* stats = (float*)(ws + 117440512);      // 768 groups x {s1,s2}

  hipMemsetAsync(stats, 0, 1536 * sizeof(float), stream);
  xpose_cast<<<dim3(32, 8, 8), 256, 0, stream>>>(x, xT);
  conv_gn<<<dim3(16, 32, 24), 256, 0, stream>>>(xT, wq, wk, wv, bq, bk, bv,
                                                Qb, Kb, Vb, stats);
  gn_apply<<<24576, 256, 0, stream>>>(Qb, stats, gw1, gb1, gw2, gb2, gw3, gb3);
  attn<<<dim3(16, 64), 256, 0, stream>>>(Qb, Kb, Vb, out);
}